// Round 2
// baseline (110.648 us; speedup 1.0000x reference)
//
#include <hip/hip_runtime.h>
#include <hip/hip_bf16.h>

typedef _Float16 f16;
typedef __attribute__((ext_vector_type(8))) _Float16 f16x8;
typedef __attribute__((ext_vector_type(4))) _Float16 f16x4;
typedef __attribute__((ext_vector_type(4))) float f32x4;

#define S_LEN 4096
#define NHEAD 8
#define HDIM 64
#define EMB 512
#define KDIM 512
#define LOG2E 1.4426950408889634f

// ---------------- cast / transpose ----------------
__global__ void cast_f32_f16_kernel(const float* __restrict__ in, f16* __restrict__ out, int n) {
  int i = (blockIdx.x * 256 + threadIdx.x) * 4;
  if (i >= n) return;
  float4 v = *(const float4*)(in + i);
  f16x4 o = { (f16)v.x, (f16)v.y, (f16)v.z, (f16)v.w };
  *(f16x4*)(out + i) = o;
}

// in [R][C] f32  ->  out [C][R] f16
__global__ void transpose_cast_kernel(const float* __restrict__ in, f16* __restrict__ out, int R, int C) {
  int idx = blockIdx.x * 256 + threadIdx.x;
  if (idx >= R * C) return;
  int r = idx / C, c = idx - r * C;
  out[(size_t)c * R + r] = (f16)in[idx];
}

// ---------------- GEMM: C[M][N] = A[M][K] * Bt[N][K]^T + bias ----------------
// MODE 0: epilogue scatters to Q (scaled 1/8), K, V^T  (QKV problem, N=1536)
// MODE 1: epilogue writes f32 C + bias                  (output projection)
#define TM 128
#define TN 128
#define TK 32
#define LDP 40  // padded LDS row (elements); 80 B = 5*16 B so 16B accesses stay aligned

template<int MODE>
__global__ __launch_bounds__(256) void gemm_bt_kernel(
    const f16* __restrict__ A, const f16* __restrict__ Bt, const float* __restrict__ bias,
    f16* __restrict__ Qo, f16* __restrict__ Ko, f16* __restrict__ Vo,
    float* __restrict__ Co, int M, int N) {
  __shared__ f16 As[TM][LDP];
  __shared__ f16 Bs[TN][LDP];
  const int m0 = blockIdx.x * TM, n0 = blockIdx.y * TN;
  const int tid = threadIdx.x;
  const int lane = tid & 63, wid = tid >> 6;
  const int wr = wid >> 1, wc = wid & 1;      // 2x2 wave grid, each wave 64x64
  const int g = lane >> 4, q16 = lane & 15;
  const int sr = tid >> 1, sh = tid & 1;      // staging: row, 16-elem half

  f32x4 zero = {0.f, 0.f, 0.f, 0.f};
  f32x4 acc[4][4];
#pragma unroll
  for (int i = 0; i < 4; i++)
#pragma unroll
    for (int j = 0; j < 4; j++) acc[i][j] = zero;

  for (int kk = 0; kk < KDIM; kk += TK) {
    // each thread stages 16 f16 (= two int4) per matrix: full 32-elem K-slice per row
    const f16* Ap = A + (size_t)(m0 + sr) * KDIM + kk + sh * 16;
    const f16* Bp = Bt + (size_t)(n0 + sr) * KDIM + kk + sh * 16;
    int4 av0 = *(const int4*)(Ap);
    int4 av1 = *(const int4*)(Ap + 8);
    int4 bv0 = *(const int4*)(Bp);
    int4 bv1 = *(const int4*)(Bp + 8);
    *(int4*)&As[sr][sh * 16]     = av0;
    *(int4*)&As[sr][sh * 16 + 8] = av1;
    *(int4*)&Bs[sr][sh * 16]     = bv0;
    *(int4*)&Bs[sr][sh * 16 + 8] = bv1;
    __syncthreads();
    f16x8 af[4], bfr[4];
#pragma unroll
    for (int i = 0; i < 4; i++) af[i] = *(const f16x8*)&As[wr * 64 + i * 16 + q16][8 * g];
#pragma unroll
    for (int j = 0; j < 4; j++) bfr[j] = *(const f16x8*)&Bs[wc * 64 + j * 16 + q16][8 * g];
#pragma unroll
    for (int i = 0; i < 4; i++)
#pragma unroll
      for (int j = 0; j < 4; j++)
        acc[i][j] = __builtin_amdgcn_mfma_f32_16x16x32_f16(af[i], bfr[j], acc[i][j], 0, 0, 0);
    __syncthreads();
  }

#pragma unroll
  for (int i = 0; i < 4; i++)
#pragma unroll
    for (int j = 0; j < 4; j++) {
      const int n = n0 + wc * 64 + j * 16 + q16;
      const float bs = bias[n];
      const int mbase = m0 + wr * 64 + i * 16 + 4 * g;  // 4 consecutive rows via regs
      if (MODE == 1) {
#pragma unroll
        for (int r = 0; r < 4; r++) Co[(size_t)(mbase + r) * N + n] = acc[i][j][r] + bs;
      } else {
        const int b = mbase >> 12, s = mbase & (S_LEN - 1);
        const int h = n / 192, rr = n - h * 192;
        const size_t bh = (size_t)b * NHEAD + h;
        if (rr < 64) {
#pragma unroll
          for (int r = 0; r < 4; r++)
            Qo[(bh * S_LEN + s + r) * HDIM + rr] = (f16)((acc[i][j][r] + bs) * 0.125f);
        } else if (rr < 128) {
#pragma unroll
          for (int r = 0; r < 4; r++)
            Ko[(bh * S_LEN + s + r) * HDIM + (rr - 64)] = (f16)(acc[i][j][r] + bs);
        } else {
          f16x4 vv = { (f16)(acc[i][j][0] + bs), (f16)(acc[i][j][1] + bs),
                       (f16)(acc[i][j][2] + bs), (f16)(acc[i][j][3] + bs) };
          *(f16x4*)(Vo + (bh * HDIM + (rr - 128)) * S_LEN + s) = vv;  // V^T: d-row, s-contig
        }
      }
    }
}

// ---------------- sliding-window flash attention ----------------
// Q,K: [bh][s][64] f16 (Q pre-scaled by 1/8); Vt: [bh][64][s] f16; out: [b][s][512] f16
__global__ __launch_bounds__(256) void attn_kernel(
    const f16* __restrict__ Q, const f16* __restrict__ K,
    const f16* __restrict__ Vt, f16* __restrict__ O) {
  const int bh = blockIdx.x >> 6, qc = blockIdx.x & 63;
  const int b = bh >> 3, h = bh & 7;
  const int wid = threadIdx.x >> 6, lane = threadIdx.x & 63;
  const int g = lane >> 4, q16 = lane & 15;
  const int qw = qc * 64 + wid * 16;  // this wave's 16 queries
  const int qg = qw + q16;            // query this lane's softmax state tracks

  const f16* Qb = Q + ((size_t)bh * S_LEN + qw) * HDIM;
  f16x8 qf0 = *(const f16x8*)(Qb + q16 * HDIM + 8 * g);        // d 0..31 slice
  f16x8 qf1 = *(const f16x8*)(Qb + q16 * HDIM + 32 + 8 * g);   // d 32..63 slice

  f32x4 zero = {0.f, 0.f, 0.f, 0.f};
  f32x4 o[4];
#pragma unroll
  for (int dt = 0; dt < 4; dt++) o[dt] = zero;
  float m_run = -1e30f, l_run = 0.f;

  for (int t = 0; t < 17; ++t) {
    const int k0 = qw - 128 + 16 * t;  // multiple of 16 -> tiles never partially OOB
    if (k0 < 0) continue;
    if (k0 >= S_LEN) break;
    const f16* Kb = K + ((size_t)bh * S_LEN + k0 + q16) * HDIM;
    f16x8 kf0 = *(const f16x8*)(Kb + 8 * g);
    f16x8 kf1 = *(const f16x8*)(Kb + 32 + 8 * g);
    // S^T[key][query]: lane reg i -> key k0+4g+i, query qw+q16
    f32x4 s = zero;
    s = __builtin_amdgcn_mfma_f32_16x16x32_f16(kf0, qf0, s, 0, 0, 0);
    s = __builtin_amdgcn_mfma_f32_16x16x32_f16(kf1, qf1, s, 0, 0, 0);

    float sv[4], mx = -1e30f;
#pragma unroll
    for (int i = 0; i < 4; i++) {
      const int kg = k0 + 4 * g + i;
      const bool valid = (kg >= qg - 128) && (kg <= qg + 128);
      sv[i] = valid ? s[i] : -1e30f;
      mx = fmaxf(mx, sv[i]);
    }
    mx = fmaxf(mx, __shfl_xor(mx, 16));
    mx = fmaxf(mx, __shfl_xor(mx, 32));
    const float mnew = fmaxf(m_run, mx);
    const float resc = exp2f((m_run - mnew) * LOG2E);
    float ps = 0.f;
    f16x4 pf;
#pragma unroll
    for (int i = 0; i < 4; i++) {
      const float p = exp2f((sv[i] - mnew) * LOG2E);
      ps += p;
      pf[i] = (f16)p;
    }
    ps += __shfl_xor(ps, 16);
    ps += __shfl_xor(ps, 32);
    l_run = l_run * resc + ps;
    m_run = mnew;
    float ri[4];
#pragma unroll
    for (int i = 0; i < 4; i++) ri[i] = __shfl(resc, 4 * g + i);
#pragma unroll
    for (int dt = 0; dt < 4; dt++) {
#pragma unroll
      for (int i = 0; i < 4; i++) o[dt][i] *= ri[i];
      f16x4 vf = *(const f16x4*)(Vt + ((size_t)bh * HDIM + dt * 16 + q16) * S_LEN + k0 + 4 * g);
      o[dt] = __builtin_amdgcn_mfma_f32_16x16x16f16(pf, vf, o[dt], 0, 0, 0);
    }
  }

  const float linv = 1.f / l_run;
  float li[4];
#pragma unroll
  for (int i = 0; i < 4; i++) li[i] = __shfl(linv, 4 * g + i);
#pragma unroll
  for (int dt = 0; dt < 4; dt++)
#pragma unroll
    for (int i = 0; i < 4; i++) {
      const int s_idx = qw + 4 * g + i;
      O[((size_t)b * S_LEN + s_idx) * EMB + h * HDIM + dt * 16 + q16] = (f16)(o[dt][i] * li[i]);
    }
}

// ---------------- launch ----------------
extern "C" void kernel_launch(void* const* d_in, const int* in_sizes, int n_in,
                              void* d_out, int out_size, void* d_ws, size_t ws_size,
                              hipStream_t stream) {
  const float* x     = (const float*)d_in[0];
  const float* w_qkv = (const float*)d_in[1];
  const float* b_qkv = (const float*)d_in[2];
  const float* w_o   = (const float*)d_in[3];
  const float* b_o   = (const float*)d_in[4];
  float* out = (float*)d_out;

  char* ws = (char*)d_ws;
  f16* xb    = (f16*)(ws);                 // [8192][512]        8.0 MiB
  f16* wqkvt = (f16*)(ws + 8388608);       // [1536][512]        1.5 MiB
  f16* wot   = (f16*)(ws + 9961472);       // [512][512]         0.5 MiB
  f16* Qs    = (f16*)(ws + 10485760);      // [16][4096][64]     8 MiB
  f16* Ks    = (f16*)(ws + 18874368);      // [16][4096][64]     8 MiB
  f16* Vt    = (f16*)(ws + 27262976);      // [16][64][4096]     8 MiB
  f16* attn  = (f16*)(ws + 35651584);      // [8192][512]        8 MiB

  cast_f32_f16_kernel<<<4096, 256, 0, stream>>>(x, xb, 8192 * 512);
  transpose_cast_kernel<<<3072, 256, 0, stream>>>(w_qkv, wqkvt, 512, 1536);
  transpose_cast_kernel<<<1024, 256, 0, stream>>>(w_o, wot, 512, 512);
  gemm_bt_kernel<0><<<dim3(64, 12), 256, 0, stream>>>(xb, wqkvt, b_qkv, Qs, Ks, Vt,
                                                      (float*)nullptr, 8192, 1536);
  attn_kernel<<<1024, 256, 0, stream>>>(Qs, Ks, Vt, attn);
  gemm_bt_kernel<1><<<dim3(64, 4), 256, 0, stream>>>(attn, wot, b_o,
                                                     (f16*)nullptr, (f16*)nullptr, (f16*)nullptr,
                                                     out, 8192, 512);
}